// Round 8
// baseline (432.198 us; speedup 1.0000x reference)
//
#include <hip/hip_runtime.h>
#include <hip/hip_bf16.h>

// Problem geometry
#define E_CNT  256
#define D_IN   15
#define HDIM   128
#define BATCH  8192
#define CPE16  (BATCH / 16)         // 512 chunks of 16 rows per expert
#define SW1    40                   // w1t row stride (80B, 16B-aligned; 20dw -> 2-way banks)
#define SW2    136                  // w2t row stride (272B, 16B-aligned; 68dw -> 2-way banks)
#define NL2E   -1.44269504088896341f

typedef float f32x4 __attribute__((ext_vector_type(4)));
typedef short bf16x8 __attribute__((ext_vector_type(8)));
typedef unsigned int uint4v __attribute__((ext_vector_type(4)));

#define MFMA16(a, b, c) __builtin_amdgcn_mfma_f32_16x16x32_bf16((a), (b), (c), 0, 0, 0)

// bf16 via round-half-up on the bit pattern (values finite here).
static __device__ inline unsigned short f2bf_rnd(float f) {
    unsigned u = __builtin_bit_cast(unsigned, f);
    return (unsigned short)((u + 0x8000u) >> 16);
}

// sigmoid with pre-scaled input az = -z*log2(e): s = rcp(1 + 2^az).
static __device__ inline float sg(float az) {
    float e = __builtin_amdgcn_exp2f(az);
    return __builtin_amdgcn_rcpf(1.0f + e);
}

// pack two floats to a bf16 pair (lo in low half), round-half-up: 3 VALU.
static __device__ inline unsigned pack2(float lo, float hi_) {
    unsigned a = __builtin_bit_cast(unsigned, lo) + 0x8000u;
    unsigned b = __builtin_bit_cast(unsigned, hi_) + 0x8000u;
#if __has_builtin(__builtin_amdgcn_perm)
    return __builtin_amdgcn_perm(b, a, 0x07060302u);   // D = {a.b2,a.b3,b.b2,b.b3}
#else
    return (a >> 16) | (b & 0xffff0000u);
#endif
}

// v_permlane32_swap_b32: a' = {a.g0,a.g1,b.g0,b.g1}, b' = {a.g2,a.g3,b.g2,b.g3}
// (g = 16-lane groups; validated on-device in rounds 3-7)
static __device__ inline void pl32swap(unsigned &a, unsigned &b) {
#if __has_builtin(__builtin_amdgcn_permlane32_swap)
    auto r = __builtin_amdgcn_permlane32_swap(a, b, false, false);
    a = (unsigned)r[0];
    b = (unsigned)r[1];
#else
    asm volatile("v_permlane32_swap_b32 %0, %1" : "+v"(a), "+v"(b));
#endif
}

// v_permlane16_swap_b32: swaps lanes 16-31 of a with lanes 0-15 of b in each
// 32-half: a' = {a.g0,b.g0,a.g2,b.g2}, b' = {a.g1,b.g1,a.g3,b.g3}
static __device__ inline void pl16swap(unsigned &a, unsigned &b) {
#if __has_builtin(__builtin_amdgcn_permlane16_swap)
    auto r = __builtin_amdgcn_permlane16_swap(a, b, false, false);
    a = (unsigned)r[0];
    b = (unsigned)r[1];
#else
    asm volatile("v_permlane16_swap_b32 %0, %1" : "+v"(a), "+v"(b));
#endif
}

static __device__ inline f32x4 zero4() { f32x4 z = {0.f, 0.f, 0.f, 0.f}; return z; }

// Redistribute two 16x16 C-tiles (pair-packed sigmoids) into one K=32 B-frag.
// C/D map: col=lane&15, row=(lane>>4)*4+reg. B-frag: col=lane&15, k=(lane>>4)*8+j.
// Quarter q needs local rows 8q..8q+7 = groups {2q,2q+1}'s data; one pl32swap +
// one pl16swap per dword pair realizes the gather (see derivation in session log).
static __device__ inline bf16x8 mk_bfrag(unsigned X0, unsigned X1, unsigned Y0, unsigned Y1) {
    pl32swap(X0, Y0);   // X0={X0g0,X0g1,Y0g0,Y0g1} Y0={X0g2,X0g3,Y0g2,Y0g3}
    pl32swap(X1, Y1);
    pl16swap(X0, Y0);   // X0={X0g0,X0g2,Y0g0,Y0g2}=j01  Y0={X0g1,X0g3,Y0g1,Y0g3}=j45
    pl16swap(X1, Y1);   // X1=j23, Y1=j67
    uint4v u = {X0, X1, Y0, Y1};
    return __builtin_bit_cast(bf16x8, u);
}

// x[B][15] f32 -> xbf[B][16] bf16 with slot 15 = 1.0 (b1 partner)
__global__ __launch_bounds__(256)
void prep_x_kernel(const float* __restrict__ x, unsigned short* __restrict__ xbf)
{
    int i = blockIdx.x * 256 + threadIdx.x;
    if (i >= BATCH * 16) return;
    int row = i >> 4, k = i & 15;
    float v = (k < D_IN) ? x[row * D_IN + k] : 1.0f;
    xbf[i] = f2bf_rnd(v);
}

// 16x16x32-fragment MFMA MLP: all accumulators 4 regs, h-frags 16 regs ->
// ~100-reg true demand fits (256,3) cap 170 without spill -> 3 blocks/CU.
// w1t row layout (scaled by -log2e): [0..14]=W1^T, [15]=b1, [16..31]=0,
// [32]=b2, [33..39]=0. L1 is ONE K=32 MFMA per 16-row h-tile (k>=16 hits the
// zero区); b2 enters L2 as a K-step whose A-frag reads col 32 (q==0) or the
// zero cols 16..23 (q>=1); w3 reads a zero-padded flat array (rows 1..15 zero).
__global__ __launch_bounds__(256, 3)
void mlp256_kernel(const float* __restrict__ x, const unsigned short* __restrict__ xbf,
                   const float* __restrict__ W1, const float* __restrict__ b1,
                   const float* __restrict__ W2, const float* __restrict__ b2,
                   const float* __restrict__ W3, const float* __restrict__ b3,
                   float* __restrict__ dst, int use_xbf, int transposed)
{
    __shared__ __align__(16) unsigned short w1t[HDIM * SW1];   // 10.2 KB
    __shared__ __align__(16) unsigned short w2t[HDIM * SW2];   // 34.8 KB
    __shared__ __align__(16) unsigned short w3l[256];          // w3 + 128 zeros

    const int tid  = threadIdx.x;
    const int wave = tid >> 6;
    const int lane = tid & 63;
    const int l15  = lane & 15;
    const int q    = lane >> 4;

    // grid = 768: e = bid&255, rg = bid>>8 (0..2). Blocks e, e+256, e+512 share
    // bid%8 -> same XCD under round-robin dispatch (one expert's W2 in one L2).
    const int bid = blockIdx.x;
    const int e   = bid & 255;
    const int rg  = bid >> 8;

    const float* w1p = W1 + e * (D_IN * HDIM);
    const float* b1p = b1 + e * HDIM;
    const float* w2p = W2 + e * (HDIM * HDIM);
    const float* b2p = b2 + e * HDIM;
    const float* w3p = W3 + e * HDIM;
    const float  b3v = b3[e];

    // ---- stage weights (prologue only) ----
    for (int i = tid; i < HDIM * 16; i += 256) {       // cols 0..15: W1^T + b1
        int h = i & 127, k = i >> 7;
        float v = (k < D_IN) ? w1p[k * HDIM + h] : b1p[h];
        w1t[h * SW1 + k] = f2bf_rnd(v * NL2E);
    }
    for (int i = tid; i < HDIM * 24; i += 256) {       // cols 16..39: zeros + b2@32
        int h = i & 127, kk = 16 + (i >> 7);
        w1t[h * SW1 + kk] = (kk == 32) ? f2bf_rnd(b2p[h] * NL2E) : (unsigned short)0;
    }
    for (int i = tid; i < HDIM * HDIM; i += 256) {     // W2^T scaled
        int h = i & 127, k = i >> 7;
        w2t[h * SW2 + k] = f2bf_rnd(w2p[k * HDIM + h] * NL2E);
    }
    if (tid < 256) w3l[tid] = (tid < HDIM) ? f2bf_rnd(w3p[tid]) : (unsigned short)0;

    bf16x8 ONEB;   // B[k==0]=1.0 (k==0 <-> q==0,j==0; other quarters' j0 multiply A-zeros)
#pragma unroll
    for (int j = 0; j < 8; ++j) ONEB[j] = 0;
    ONEB[0] = (short)0x3F80;

    __syncthreads();   // weights staged; waves independent from here

    // per-lane bases
    const unsigned short* w1base = w1t + l15 * SW1 + q * 8;                  // + t*16*SW1
    const unsigned short* b2base = w1t + l15 * SW1 + ((q == 0) ? 32 : 16);   // + t*16*SW1
    const unsigned short* w2base = w2t + l15 * SW2 + q * 8;                  // + ot*16*SW2 + kb*32
    const unsigned short* w3base = w3l + ((l15 == 0) ? 0 : 128) + q * 8;     // + kb*32
    const int xoff = l15 * 16 + (q & 1) * 8;

    // chunks: c ≡ rg (mod 3), split across the 4 waves
    for (int c = rg + 3 * wave; c < CPE16; c += 12) {
        // x B-frag: col=l15 -> batch row c*16+l15; k(q,j)=q*8+j; quarters 2,3
        // replicate 0,1 (don't-care: w1t k>=16 is zero)
        bf16x8 XB;
        if (use_xbf) {
            XB = *reinterpret_cast<const bf16x8*>(xbf + (size_t)c * 256 + xoff);
        } else {
            const float* xp = x + (size_t)(c * 16 + l15) * D_IN;
#pragma unroll
            for (int j = 0; j < 8; ++j) {
                int k = (q & 1) * 8 + j;
                XB[j] = (short)f2bf_rnd((k < D_IN) ? xp[k] : 1.0f);
            }
        }

        // ---- layer 1: 8 h-tiles, one K=32 MFMA each; sigmoid-pair-pack ----
        unsigned P0[8], P1[8];
#pragma unroll
        for (int t = 0; t < 8; ++t) {
            bf16x8 wa = *reinterpret_cast<const bf16x8*>(w1base + t * 16 * SW1);
            f32x4 a1 = MFMA16(wa, XB, zero4());
            P0[t] = pack2(sg(a1[0]), sg(a1[1]));   // rows 4q+0,1 of tile t
            P1[t] = pack2(sg(a1[2]), sg(a1[3]));   // rows 4q+2,3
        }
        // redistribute -> 4 K=32 B-frags
        bf16x8 H1[4];
#pragma unroll
        for (int kb = 0; kb < 4; ++kb)
            H1[kb] = mk_bfrag(P0[2 * kb], P1[2 * kb], P0[2 * kb + 1], P1[2 * kb + 1]);

        // ---- layer 2: 8 out-tiles x (b2 K-step + 4 K-steps) ----
        unsigned Q0[8], Q1[8];
#pragma unroll
        for (int ot = 0; ot < 8; ++ot) {
            bf16x8 wb = *reinterpret_cast<const bf16x8*>(b2base + ot * 16 * SW1);
            f32x4 c2 = MFMA16(wb, ONEB, zero4());
#pragma unroll
            for (int kb = 0; kb < 4; ++kb) {
                bf16x8 wa = *reinterpret_cast<const bf16x8*>(w2base + ot * 16 * SW2 + kb * 32);
                c2 = MFMA16(wa, H1[kb], c2);
            }
            Q0[ot] = pack2(sg(c2[0]), sg(c2[1]));
            Q1[ot] = pack2(sg(c2[2]), sg(c2[3]));
        }

        // ---- layer 3: redistribute h2, 4 MFMAs against zero-padded w3 ----
        f32x4 o3 = zero4();
#pragma unroll
        for (int kb = 0; kb < 4; ++kb) {
            bf16x8 H2 = mk_bfrag(Q0[2 * kb], Q1[2 * kb], Q0[2 * kb + 1], Q1[2 * kb + 1]);
            bf16x8 w3f = *reinterpret_cast<const bf16x8*>(w3base + kb * 32);
            o3 = MFMA16(w3f, H2, o3);
        }

        if (q == 0) {   // output row 0 = quarter 0, reg 0; col = l15
            float v = o3[0] + b3v;
            const int bb = c * 16 + l15;
            if (transposed) dst[(size_t)e * BATCH + bb] = v;
            else            dst[(size_t)bb * E_CNT + e] = v;
        }
    }
}

// wsT[e][b] (256 x 8192) -> out[b][e] (8192 x 256), 64x64 LDS tiles
__global__ __launch_bounds__(256)
void transpose_out_kernel(const float* __restrict__ wsT, float* __restrict__ out)
{
    __shared__ float tile[64][65];
    const int tx = threadIdx.x & 63;
    const int ty = threadIdx.x >> 6;
    const int b0 = blockIdx.x * 64;
    const int e0 = blockIdx.y * 64;
#pragma unroll
    for (int r = ty; r < 64; r += 4)
        tile[r][tx] = wsT[(size_t)(e0 + r) * BATCH + b0 + tx];
    __syncthreads();
#pragma unroll
    for (int r = ty; r < 64; r += 4)
        out[(size_t)(b0 + r) * E_CNT + e0 + tx] = tile[tx][r];
}

extern "C" void kernel_launch(void* const* d_in, const int* in_sizes, int n_in,
                              void* d_out, int out_size, void* d_ws, size_t ws_size,
                              hipStream_t stream) {
    const float* x  = (const float*)d_in[0];
    const float* W1 = (const float*)d_in[1];
    const float* b1 = (const float*)d_in[2];
    const float* W2 = (const float*)d_in[3];
    const float* b2 = (const float*)d_in[4];
    const float* W3 = (const float*)d_in[5];
    const float* b3 = (const float*)d_in[6];
    float* out = (float*)d_out;

    const size_t XBF_BYTES = (size_t)BATCH * 16 * sizeof(unsigned short);  // 256 KB
    const size_t WST_BYTES = (size_t)E_CNT * BATCH * sizeof(float);        // 8 MB

    const bool have_xbf = ws_size >= XBF_BYTES + WST_BYTES;
    const bool have_wst = ws_size >= WST_BYTES;

    unsigned short* xbf = (unsigned short*)d_ws;
    float* wsT = have_xbf ? (float*)((char*)d_ws + XBF_BYTES) : (float*)d_ws;

    if (have_xbf)
        prep_x_kernel<<<dim3((BATCH * 16 + 255) / 256), dim3(256), 0, stream>>>(x, xbf);

    if (have_wst) {
        mlp256_kernel<<<dim3(E_CNT * 3), dim3(256), 0, stream>>>(
            x, xbf, W1, b1, W2, b2, W3, b3, wsT, have_xbf ? 1 : 0, 1);
        transpose_out_kernel<<<dim3(BATCH / 64, E_CNT / 64), dim3(256), 0, stream>>>(
            wsT, out);
    } else {
        mlp256_kernel<<<dim3(E_CNT * 3), dim3(256), 0, stream>>>(
            x, xbf, W1, b1, W2, b2, W3, b3, out, 0, 0);
    }
}

// Round 9
// 182.015 us; speedup vs baseline: 2.3745x; 2.3745x over previous
//
#include <hip/hip_runtime.h>
#include <hip/hip_bf16.h>

// Problem geometry
#define E_CNT  256
#define D_IN   15
#define HDIM   128
#define BATCH  8192
#define CPE16  (BATCH / 16)         // 512 chunks of 16 rows per expert
#define SW1    40                   // w1t row stride (80B, 16B-aligned)
#define SW2    136                  // w2t row stride (272B, 16B-aligned)
#define NL2E   -1.44269504088896341f

typedef float f32x4 __attribute__((ext_vector_type(4)));
typedef short bf16x8 __attribute__((ext_vector_type(8)));
typedef unsigned int uint4v __attribute__((ext_vector_type(4)));

#define MFMA16(a, b, c) __builtin_amdgcn_mfma_f32_16x16x32_bf16((a), (b), (c), 0, 0, 0)
#define SCHED_FENCE() __builtin_amdgcn_sched_barrier(0)

// bf16 via round-half-up on the bit pattern (values finite here).
static __device__ inline unsigned short f2bf_rnd(float f) {
    unsigned u = __builtin_bit_cast(unsigned, f);
    return (unsigned short)((u + 0x8000u) >> 16);
}

// sigmoid with pre-scaled input az = -z*log2(e): s = rcp(1 + 2^az).
static __device__ inline float sg(float az) {
    float e = __builtin_amdgcn_exp2f(az);
    return __builtin_amdgcn_rcpf(1.0f + e);
}

// pack two floats to a bf16 pair (lo in low half), round-half-up: 3 VALU.
static __device__ inline unsigned pack2(float lo, float hi_) {
    unsigned a = __builtin_bit_cast(unsigned, lo) + 0x8000u;
    unsigned b = __builtin_bit_cast(unsigned, hi_) + 0x8000u;
#if __has_builtin(__builtin_amdgcn_perm)
    return __builtin_amdgcn_perm(b, a, 0x07060302u);   // D = {a.b2,a.b3,b.b2,b.b3}
#else
    return (a >> 16) | (b & 0xffff0000u);
#endif
}

// v_permlane32_swap_b32: a' = {a.g0,a.g1,b.g0,b.g1}, b' = {a.g2,a.g3,b.g2,b.g3}
static __device__ inline void pl32swap(unsigned &a, unsigned &b) {
#if __has_builtin(__builtin_amdgcn_permlane32_swap)
    auto r = __builtin_amdgcn_permlane32_swap(a, b, false, false);
    a = (unsigned)r[0];
    b = (unsigned)r[1];
#else
    asm volatile("v_permlane32_swap_b32 %0, %1" : "+v"(a), "+v"(b));
#endif
}

// v_permlane16_swap_b32: a' = {a.g0,b.g0,a.g2,b.g2}, b' = {a.g1,b.g1,a.g3,b.g3}
static __device__ inline void pl16swap(unsigned &a, unsigned &b) {
#if __has_builtin(__builtin_amdgcn_permlane16_swap)
    auto r = __builtin_amdgcn_permlane16_swap(a, b, false, false);
    a = (unsigned)r[0];
    b = (unsigned)r[1];
#else
    asm volatile("v_permlane16_swap_b32 %0, %1" : "+v"(a), "+v"(b));
#endif
}

static __device__ inline f32x4 zero4() { f32x4 z = {0.f, 0.f, 0.f, 0.f}; return z; }

// Redistribute two 16x16 C-tiles (pair-packed sigmoids) into one K=32 B-frag.
// C/D map: col=lane&15, row=(lane>>4)*4+reg. B-frag: col=lane&15, k=(lane>>4)*8+j.
// (validated on-device in R8: absmax 0.0078)
static __device__ inline bf16x8 mk_bfrag(unsigned X0, unsigned X1, unsigned Y0, unsigned Y1) {
    pl32swap(X0, Y0);
    pl32swap(X1, Y1);
    pl16swap(X0, Y0);
    pl16swap(X1, Y1);
    uint4v u = {X0, X1, Y0, Y1};
    return __builtin_bit_cast(bf16x8, u);
}

// x[B][15] f32 -> xbf[B][16] bf16 with slot 15 = 1.0 (b1 partner)
__global__ __launch_bounds__(256)
void prep_x_kernel(const float* __restrict__ x, unsigned short* __restrict__ xbf)
{
    int i = blockIdx.x * 256 + threadIdx.x;
    if (i >= BATCH * 16) return;
    int row = i >> 4, k = i & 15;
    float v = (k < D_IN) ? x[row * D_IN + k] : 1.0f;
    xbf[i] = f2bf_rnd(v);
}

// 16x16x32-fragment MFMA MLP, pairwise phase-fused + sched_barrier-fenced so
// the register live-set stays ~70 regs (no scheduler hoist-spill) and the
// (256,3) cap 170 holds -> 3 blocks/CU -> 3 waves/SIMD.
// w1t row layout (scaled by -log2e): [0..14]=W1^T, [15]=b1, [16..31]=0,
// [32]=b2, [33..39]=0.
__global__ __launch_bounds__(256, 3)
void mlp256_kernel(const float* __restrict__ x, const unsigned short* __restrict__ xbf,
                   const float* __restrict__ W1, const float* __restrict__ b1,
                   const float* __restrict__ W2, const float* __restrict__ b2,
                   const float* __restrict__ W3, const float* __restrict__ b3,
                   float* __restrict__ dst, int use_xbf, int transposed)
{
    __shared__ __align__(16) unsigned short w1t[HDIM * SW1];   // 10.2 KB
    __shared__ __align__(16) unsigned short w2t[HDIM * SW2];   // 34.8 KB
    __shared__ __align__(16) unsigned short w3l[256];          // w3 + 128 zeros

    const int tid  = threadIdx.x;
    const int wave = tid >> 6;
    const int lane = tid & 63;
    const int l15  = lane & 15;
    const int q    = lane >> 4;

    // grid = 768: e = bid&255, rg = bid>>8 (0..2). Blocks e, e+256, e+512 share
    // bid%8 -> same XCD under round-robin dispatch (one expert's W2 in one L2).
    const int bid = blockIdx.x;
    const int e   = bid & 255;
    const int rg  = bid >> 8;

    const float* w1p = W1 + e * (D_IN * HDIM);
    const float* b1p = b1 + e * HDIM;
    const float* w2p = W2 + e * (HDIM * HDIM);
    const float* b2p = b2 + e * HDIM;
    const float* w3p = W3 + e * HDIM;
    const float  b3v = b3[e];

    // ---- stage weights (prologue only) ----
    for (int i = tid; i < HDIM * 16; i += 256) {       // cols 0..15: W1^T + b1
        int h = i & 127, k = i >> 7;
        float v = (k < D_IN) ? w1p[k * HDIM + h] : b1p[h];
        w1t[h * SW1 + k] = f2bf_rnd(v * NL2E);
    }
    for (int i = tid; i < HDIM * 24; i += 256) {       // cols 16..39: zeros + b2@32
        int h = i & 127, kk = 16 + (i >> 7);
        w1t[h * SW1 + kk] = (kk == 32) ? f2bf_rnd(b2p[h] * NL2E) : (unsigned short)0;
    }
    for (int i = tid; i < HDIM * HDIM; i += 256) {     // W2^T scaled
        int h = i & 127, k = i >> 7;
        w2t[h * SW2 + k] = f2bf_rnd(w2p[k * HDIM + h] * NL2E);
    }
    if (tid < 256) w3l[tid] = (tid < HDIM) ? f2bf_rnd(w3p[tid]) : (unsigned short)0;

    bf16x8 ONEB;   // B[k==0]=1.0 (other quarters' j0 multiply A-zeros)
#pragma unroll
    for (int j = 0; j < 8; ++j) ONEB[j] = 0;
    ONEB[0] = (short)0x3F80;

    __syncthreads();   // weights staged; waves independent from here

    // per-lane bases
    const unsigned short* w1base = w1t + l15 * SW1 + q * 8;                  // + t*16*SW1
    const unsigned short* b2base = w1t + l15 * SW1 + ((q == 0) ? 32 : 16);   // + ot*16*SW1
    const unsigned short* w2base = w2t + l15 * SW2 + q * 8;                  // + ot*16*SW2 + kb*32
    const unsigned short* w3base = w3l + ((l15 == 0) ? 0 : 128) + q * 8;     // + pt*32
    const int xoff = l15 * 16 + (q & 1) * 8;

    // chunks: c ≡ rg (mod 3), split across the 4 waves
    for (int c = rg + 3 * wave; c < CPE16; c += 12) {
        // x B-frag: col=l15 -> batch row c*16+l15; quarters 2,3 replicate 0,1
        // (don't-care: w1t k>=16 is zero)
        bf16x8 XB;
        if (use_xbf) {
            XB = *reinterpret_cast<const bf16x8*>(xbf + (size_t)c * 256 + xoff);
        } else {
            const float* xp = x + (size_t)(c * 16 + l15) * D_IN;
#pragma unroll
            for (int j = 0; j < 8; ++j) {
                int k = (q & 1) * 8 + j;
                XB[j] = (short)f2bf_rnd((k < D_IN) ? xp[k] : 1.0f);
            }
        }

        // ---- layer 1, pairwise: two 16-wide h-tiles -> one K=32 B-frag ----
        bf16x8 H1[4];
#pragma unroll
        for (int kb = 0; kb < 4; ++kb) {
            bf16x8 wa0 = *reinterpret_cast<const bf16x8*>(w1base + (2 * kb)     * 16 * SW1);
            f32x4 aa = MFMA16(wa0, XB, zero4());
            unsigned p0 = pack2(sg(aa[0]), sg(aa[1]));
            unsigned p1 = pack2(sg(aa[2]), sg(aa[3]));
            bf16x8 wa1 = *reinterpret_cast<const bf16x8*>(w1base + (2 * kb + 1) * 16 * SW1);
            f32x4 ab = MFMA16(wa1, XB, zero4());
            unsigned p2 = pack2(sg(ab[0]), sg(ab[1]));
            unsigned p3 = pack2(sg(ab[2]), sg(ab[3]));
            H1[kb] = mk_bfrag(p0, p1, p2, p3);
            SCHED_FENCE();
        }

        // ---- layer 2 + layer 3, pairwise: two out-tiles -> one L3 K-step ----
        f32x4 o3 = zero4();
#pragma unroll
        for (int pt = 0; pt < 4; ++pt) {
            unsigned q0, q1, q2, q3;
            {
                const int ot = 2 * pt;
                bf16x8 wb = *reinterpret_cast<const bf16x8*>(b2base + ot * 16 * SW1);
                f32x4 c2 = MFMA16(wb, ONEB, zero4());
#pragma unroll
                for (int kb = 0; kb < 4; ++kb) {
                    bf16x8 wa = *reinterpret_cast<const bf16x8*>(w2base + ot * 16 * SW2 + kb * 32);
                    c2 = MFMA16(wa, H1[kb], c2);
                }
                q0 = pack2(sg(c2[0]), sg(c2[1]));
                q1 = pack2(sg(c2[2]), sg(c2[3]));
            }
            SCHED_FENCE();
            {
                const int ot = 2 * pt + 1;
                bf16x8 wb = *reinterpret_cast<const bf16x8*>(b2base + ot * 16 * SW1);
                f32x4 c2 = MFMA16(wb, ONEB, zero4());
#pragma unroll
                for (int kb = 0; kb < 4; ++kb) {
                    bf16x8 wa = *reinterpret_cast<const bf16x8*>(w2base + ot * 16 * SW2 + kb * 32);
                    c2 = MFMA16(wa, H1[kb], c2);
                }
                q2 = pack2(sg(c2[0]), sg(c2[1]));
                q3 = pack2(sg(c2[2]), sg(c2[3]));
            }
            bf16x8 H2 = mk_bfrag(q0, q1, q2, q3);
            bf16x8 w3f = *reinterpret_cast<const bf16x8*>(w3base + pt * 32);
            o3 = MFMA16(w3f, H2, o3);
            SCHED_FENCE();
        }

        if (q == 0) {   // output row 0 = quarter 0, reg 0; col = l15
            float v = o3[0] + b3v;
            const int bb = c * 16 + l15;
            if (transposed) dst[(size_t)e * BATCH + bb] = v;
            else            dst[(size_t)bb * E_CNT + e] = v;
        }
    }
}

// wsT[e][b] (256 x 8192) -> out[b][e] (8192 x 256), 64x64 LDS tiles
__global__ __launch_bounds__(256)
void transpose_out_kernel(const float* __restrict__ wsT, float* __restrict__ out)
{
    __shared__ float tile[64][65];
    const int tx = threadIdx.x & 63;
    const int ty = threadIdx.x >> 6;
    const int b0 = blockIdx.x * 64;
    const int e0 = blockIdx.y * 64;
#pragma unroll
    for (int r = ty; r < 64; r += 4)
        tile[r][tx] = wsT[(size_t)(e0 + r) * BATCH + b0 + tx];
    __syncthreads();
#pragma unroll
    for (int r = ty; r < 64; r += 4)
        out[(size_t)(b0 + r) * E_CNT + e0 + tx] = tile[tx][r];
}

extern "C" void kernel_launch(void* const* d_in, const int* in_sizes, int n_in,
                              void* d_out, int out_size, void* d_ws, size_t ws_size,
                              hipStream_t stream) {
    const float* x  = (const float*)d_in[0];
    const float* W1 = (const float*)d_in[1];
    const float* b1 = (const float*)d_in[2];
    const float* W2 = (const float*)d_in[3];
    const float* b2 = (const float*)d_in[4];
    const float* W3 = (const float*)d_in[5];
    const float* b3 = (const float*)d_in[6];
    float* out = (float*)d_out;

    const size_t XBF_BYTES = (size_t)BATCH * 16 * sizeof(unsigned short);  // 256 KB
    const size_t WST_BYTES = (size_t)E_CNT * BATCH * sizeof(float);        // 8 MB

    const bool have_xbf = ws_size >= XBF_BYTES + WST_BYTES;
    const bool have_wst = ws_size >= WST_BYTES;

    unsigned short* xbf = (unsigned short*)d_ws;
    float* wsT = have_xbf ? (float*)((char*)d_ws + XBF_BYTES) : (float*)d_ws;

    if (have_xbf)
        prep_x_kernel<<<dim3((BATCH * 16 + 255) / 256), dim3(256), 0, stream>>>(x, xbf);

    if (have_wst) {
        mlp256_kernel<<<dim3(E_CNT * 3), dim3(256), 0, stream>>>(
            x, xbf, W1, b1, W2, b2, W3, b3, wsT, have_xbf ? 1 : 0, 1);
        transpose_out_kernel<<<dim3(BATCH / 64, E_CNT / 64), dim3(256), 0, stream>>>(
            wsT, out);
    } else {
        mlp256_kernel<<<dim3(E_CNT * 3), dim3(256), 0, stream>>>(
            x, xbf, W1, b1, W2, b2, W3, b3, out, 0, 0);
    }
}

// Round 10
// 172.266 us; speedup vs baseline: 2.5089x; 1.0566x over previous
//
#include <hip/hip_runtime.h>
#include <hip/hip_bf16.h>

// Problem geometry
#define E_CNT  256
#define D_IN   15
#define HDIM   128
#define BATCH  8192
#define NPAIR  256                  // 256 pairs of 16-row chunks per expert
#define NL2E   -1.44269504088896341f

typedef float f32x4 __attribute__((ext_vector_type(4)));
typedef short bf16x8 __attribute__((ext_vector_type(8)));
typedef unsigned int uint4v __attribute__((ext_vector_type(4)));

#define MFMA16(a, b, c) __builtin_amdgcn_mfma_f32_16x16x32_bf16((a), (b), (c), 0, 0, 0)
#define SCHED_FENCE() __builtin_amdgcn_sched_barrier(0)

// bf16 via round-half-up on the bit pattern (values finite here).
static __device__ inline unsigned short f2bf_rnd(float f) {
    unsigned u = __builtin_bit_cast(unsigned, f);
    return (unsigned short)((u + 0x8000u) >> 16);
}

// sigmoid with pre-scaled input az = -z*log2(e): s = rcp(1 + 2^az).
static __device__ inline float sg(float az) {
    float e = __builtin_amdgcn_exp2f(az);
    return __builtin_amdgcn_rcpf(1.0f + e);
}

// pack two floats to a bf16 pair (lo in low half), round-half-up: 3 VALU.
static __device__ inline unsigned pack2(float lo, float hi_) {
    unsigned a = __builtin_bit_cast(unsigned, lo) + 0x8000u;
    unsigned b = __builtin_bit_cast(unsigned, hi_) + 0x8000u;
#if __has_builtin(__builtin_amdgcn_perm)
    return __builtin_amdgcn_perm(b, a, 0x07060302u);   // D = {a.b2,a.b3,b.b2,b.b3}
#else
    return (a >> 16) | (b & 0xffff0000u);
#endif
}

// v_permlane32_swap_b32: a' = {a.g0,a.g1,b.g0,b.g1}, b' = {a.g2,a.g3,b.g2,b.g3}
static __device__ inline void pl32swap(unsigned &a, unsigned &b) {
#if __has_builtin(__builtin_amdgcn_permlane32_swap)
    auto r = __builtin_amdgcn_permlane32_swap(a, b, false, false);
    a = (unsigned)r[0];
    b = (unsigned)r[1];
#else
    asm volatile("v_permlane32_swap_b32 %0, %1" : "+v"(a), "+v"(b));
#endif
}

// v_permlane16_swap_b32: a' = {a.g0,b.g0,a.g2,b.g2}, b' = {a.g1,b.g1,a.g3,b.g3}
static __device__ inline void pl16swap(unsigned &a, unsigned &b) {
#if __has_builtin(__builtin_amdgcn_permlane16_swap)
    auto r = __builtin_amdgcn_permlane16_swap(a, b, false, false);
    a = (unsigned)r[0];
    b = (unsigned)r[1];
#else
    asm volatile("v_permlane16_swap_b32 %0, %1" : "+v"(a), "+v"(b));
#endif
}

static __device__ inline f32x4 zero4() { f32x4 z = {0.f, 0.f, 0.f, 0.f}; return z; }

// Redistribute two 16x16 C-tiles (pair-packed sigmoids) into one K=32 B-frag.
// (validated on-device in R8/R9: absmax 0.0078)
static __device__ inline bf16x8 mk_bfrag(unsigned X0, unsigned X1, unsigned Y0, unsigned Y1) {
    pl32swap(X0, Y0);
    pl32swap(X1, Y1);
    pl16swap(X0, Y0);
    pl16swap(X1, Y1);
    uint4v u = {X0, X1, Y0, Y1};
    return __builtin_bit_cast(bf16x8, u);
}

// x[B][15] f32 -> xbf[B][16] bf16 with slot 15 = 1.0 (b1 partner)
__global__ __launch_bounds__(256)
void prep_x_kernel(const float* __restrict__ x, unsigned short* __restrict__ xbf)
{
    int i = blockIdx.x * 256 + threadIdx.x;
    if (i >= BATCH * 16) return;
    int row = i >> 4, k = i & 15;
    float v = (k < D_IN) ? x[row * D_IN + k] : 1.0f;
    xbf[i] = f2bf_rnd(v);
}

// 16x16x32 MFMA MLP, dual-chunk (32 rows/iter), FRAGMENT-ORDERED LDS:
// every A-frag is stored so lane i reads base + tile*1024B + i*16B ->
// consecutive lanes hit consecutive 16B lines: zero bank conflicts, one
// shared per-lane base. Each weight read feeds BOTH chunks' MFMAs (weight
// LDS traffic halves vs R9). Pairwise fusion + sched fences keep the live
// set ~100 regs so (256,3) holds without spill (R9-proven technique).
// Frag layouts (all scaled by -log2e except w3):
//  w1f: 8 tiles t: lane(q,l15) j -> W1T[k=q*8+j][h=t*16+l15]; k==15 = b1; k>=16 = 0
//  w2f: 32 tiles (ot,kb): j -> W2T[h=ot*16+l15][k=kb*32+q*8+j]
//  b2f: 8 tiles ot: only (q==0,j==0) nonzero = b2[ot*16+l15]
//  w3f: 4 tiles kb: only l15==0 rows nonzero = w3[kb*32+q*8+j] (unscaled)
__global__ __launch_bounds__(256, 3)
void mlp256_kernel(const float* __restrict__ x, const unsigned short* __restrict__ xbf,
                   const float* __restrict__ W1, const float* __restrict__ b1,
                   const float* __restrict__ W2, const float* __restrict__ b2,
                   const float* __restrict__ W3, const float* __restrict__ b3,
                   float* __restrict__ dst, int use_xbf, int transposed)
{
    __shared__ __align__(16) unsigned short w2f[32 * 512];   // 32 KB
    __shared__ __align__(16) unsigned short w1f[8 * 512];    // 8 KB
    __shared__ __align__(16) unsigned short b2f[8 * 512];    // 8 KB
    __shared__ __align__(16) unsigned short w3f[4 * 512];    // 4 KB

    const int tid  = threadIdx.x;
    const int wave = tid >> 6;
    const int lane = tid & 63;
    const int l15  = lane & 15;
    const int q    = lane >> 4;

    // grid = 768: e = bid&255, rg = bid>>8 (0..2). Blocks e, e+256, e+512 share
    // bid%8 -> same XCD under round-robin dispatch (one expert's W2 in one L2).
    const int bid = blockIdx.x;
    const int e   = bid & 255;
    const int rg  = bid >> 8;

    const float* w1p = W1 + e * (D_IN * HDIM);
    const float* b1p = b1 + e * HDIM;
    const float* w2p = W2 + e * (HDIM * HDIM);
    const float* b2p = b2 + e * HDIM;
    const float* w3p = W3 + e * HDIM;
    const float  b3v = b3[e];

    // ---- stage weights, fragment-ordered (prologue only) ----
    // W2: src (h,k) -> tile (h>>4)*4 + (k>>5), lane ((k>>3)&3)*16 + (h&15), j k&7
    for (int i = tid; i < HDIM * HDIM; i += 256) {
        int h = i & 127, k = i >> 7;
        int t = ((h >> 4) << 2) + (k >> 5);
        int ln = (((k >> 3) & 3) << 4) + (h & 15);
        w2f[t * 512 + ln * 8 + (k & 7)] = f2bf_rnd(w2p[k * HDIM + h] * NL2E);
    }
    // W1 (+b1, +zero upper K half): k in 0..31
    for (int i = tid; i < HDIM * 32; i += 256) {
        int h = i & 127, k = i >> 7;
        float v = (k < D_IN) ? w1p[k * HDIM + h] * NL2E
                : (k == D_IN) ? b1p[h] * NL2E : 0.0f;
        int t = h >> 4;
        int ln = (((k >> 3) & 3) << 4) + (h & 15);
        w1f[t * 512 + ln * 8 + (k & 7)] = f2bf_rnd(v);
    }
    // zeros for b2f / w3f
    for (int i = tid; i < 8 * 512; i += 256) b2f[i] = 0;
    for (int i = tid; i < 4 * 512; i += 256) w3f[i] = 0;
    __syncthreads();
    // b2 values: tile i>>4, lane (i&15) (q==0), j=0
    if (tid < HDIM)
        b2f[(tid >> 4) * 512 + (tid & 15) * 8] = f2bf_rnd(b2p[tid] * NL2E);
    // w3 values: tile i>>5, lane ((i>>3)&3)*16 + 0, j = i&7
    if (tid < HDIM)
        w3f[(tid >> 5) * 512 + (((tid >> 3) & 3) << 4) * 8 + (tid & 7)] = f2bf_rnd(w3p[tid]);

    bf16x8 ONEB;   // B[k==0]=1.0 (bias A-frag is zero for k!=0, so j0 of q>0 is don't-care)
#pragma unroll
    for (int j = 0; j < 8; ++j) ONEB[j] = 0;
    ONEB[0] = (short)0x3F80;

    __syncthreads();   // weights staged; waves independent from here

    // shared per-lane fragment base (conflict-free: lane i -> byte i*16)
    const unsigned short* w1B = w1f + lane * 8;
    const unsigned short* w2B = w2f + lane * 8;
    const unsigned short* b2B = b2f + lane * 8;
    const unsigned short* w3B = w3f + lane * 8;
    const int xoff = l15 * 16 + (q & 1) * 8;

    // pairs: p ≡ rg (mod 3), split across the 4 waves; pair p -> chunks 2p, 2p+1
    for (int p = rg + 3 * wave; p < NPAIR; p += 12) {
        const int cA = 2 * p, cB = 2 * p + 1;

        bf16x8 XA, XBv;
        if (use_xbf) {
            XA  = *reinterpret_cast<const bf16x8*>(xbf + (size_t)cA * 256 + xoff);
            XBv = *reinterpret_cast<const bf16x8*>(xbf + (size_t)cB * 256 + xoff);
        } else {
            const float* xa = x + (size_t)(cA * 16 + l15) * D_IN;
            const float* xb = x + (size_t)(cB * 16 + l15) * D_IN;
#pragma unroll
            for (int j = 0; j < 8; ++j) {
                int k = (q & 1) * 8 + j;
                XA[j]  = (short)f2bf_rnd((k < D_IN) ? xa[k] : 1.0f);
                XBv[j] = (short)f2bf_rnd((k < D_IN) ? xb[k] : 1.0f);
            }
        }

        // ---- layer 1, pairwise: two h-tiles -> one K=32 B-frag, both chunks ----
        bf16x8 H1A[4], H1B[4];
#pragma unroll
        for (int kb = 0; kb < 4; ++kb) {
            bf16x8 wa0 = *reinterpret_cast<const bf16x8*>(w1B + (2 * kb) * 512);
            f32x4 aa = MFMA16(wa0, XA,  zero4());
            f32x4 ba = MFMA16(wa0, XBv, zero4());
            bf16x8 wa1 = *reinterpret_cast<const bf16x8*>(w1B + (2 * kb + 1) * 512);
            f32x4 ab = MFMA16(wa1, XA,  zero4());
            f32x4 bb = MFMA16(wa1, XBv, zero4());
            unsigned pa0 = pack2(sg(aa[0]), sg(aa[1]));
            unsigned pa1 = pack2(sg(aa[2]), sg(aa[3]));
            unsigned pa2 = pack2(sg(ab[0]), sg(ab[1]));
            unsigned pa3 = pack2(sg(ab[2]), sg(ab[3]));
            H1A[kb] = mk_bfrag(pa0, pa1, pa2, pa3);
            unsigned pb0 = pack2(sg(ba[0]), sg(ba[1]));
            unsigned pb1 = pack2(sg(ba[2]), sg(ba[3]));
            unsigned pb2 = pack2(sg(bb[0]), sg(bb[1]));
            unsigned pb3 = pack2(sg(bb[2]), sg(bb[3]));
            H1B[kb] = mk_bfrag(pb0, pb1, pb2, pb3);
            SCHED_FENCE();
        }

        // ---- layer 2 + layer 3, pairwise: two out-tiles -> one L3 K-step ----
        f32x4 o3A = zero4(), o3B = zero4();
#pragma unroll
        for (int pt = 0; pt < 4; ++pt) {
            unsigned qa0, qa1, qa2, qa3, qb0, qb1, qb2, qb3;
            {
                const int ot = 2 * pt;
                bf16x8 wb = *reinterpret_cast<const bf16x8*>(b2B + ot * 512);
                f32x4 cA2 = MFMA16(wb, ONEB, zero4());
                f32x4 cB2 = MFMA16(wb, ONEB, zero4());
#pragma unroll
                for (int kb = 0; kb < 4; ++kb) {
                    bf16x8 wa = *reinterpret_cast<const bf16x8*>(w2B + (ot * 4 + kb) * 512);
                    cA2 = MFMA16(wa, H1A[kb], cA2);
                    cB2 = MFMA16(wa, H1B[kb], cB2);
                }
                qa0 = pack2(sg(cA2[0]), sg(cA2[1]));
                qa1 = pack2(sg(cA2[2]), sg(cA2[3]));
                qb0 = pack2(sg(cB2[0]), sg(cB2[1]));
                qb1 = pack2(sg(cB2[2]), sg(cB2[3]));
            }
            SCHED_FENCE();
            {
                const int ot = 2 * pt + 1;
                bf16x8 wb = *reinterpret_cast<const bf16x8*>(b2B + ot * 512);
                f32x4 cA2 = MFMA16(wb, ONEB, zero4());
                f32x4 cB2 = MFMA16(wb, ONEB, zero4());
#pragma unroll
                for (int kb = 0; kb < 4; ++kb) {
                    bf16x8 wa = *reinterpret_cast<const bf16x8*>(w2B + (ot * 4 + kb) * 512);
                    cA2 = MFMA16(wa, H1A[kb], cA2);
                    cB2 = MFMA16(wa, H1B[kb], cB2);
                }
                qa2 = pack2(sg(cA2[0]), sg(cA2[1]));
                qa3 = pack2(sg(cA2[2]), sg(cA2[3]));
                qb2 = pack2(sg(cB2[0]), sg(cB2[1]));
                qb3 = pack2(sg(cB2[2]), sg(cB2[3]));
            }
            bf16x8 w3a = *reinterpret_cast<const bf16x8*>(w3B + pt * 512);
            bf16x8 H2A = mk_bfrag(qa0, qa1, qa2, qa3);
            o3A = MFMA16(w3a, H2A, o3A);
            bf16x8 H2B = mk_bfrag(qb0, qb1, qb2, qb3);
            o3B = MFMA16(w3a, H2B, o3B);
            SCHED_FENCE();
        }

        if (q == 0) {   // output row 0 = quarter 0, reg 0; col = l15
            float vA = o3A[0] + b3v;
            float vB = o3B[0] + b3v;
            const int bbA = cA * 16 + l15;
            const int bbB = cB * 16 + l15;
            if (transposed) {
                dst[(size_t)e * BATCH + bbA] = vA;
                dst[(size_t)e * BATCH + bbB] = vB;
            } else {
                dst[(size_t)bbA * E_CNT + e] = vA;
                dst[(size_t)bbB * E_CNT + e] = vB;
            }
        }
    }
}

// wsT[e][b] (256 x 8192) -> out[b][e] (8192 x 256), 64x64 LDS tiles
__global__ __launch_bounds__(256)
void transpose_out_kernel(const float* __restrict__ wsT, float* __restrict__ out)
{
    __shared__ float tile[64][65];
    const int tx = threadIdx.x & 63;
    const int ty = threadIdx.x >> 6;
    const int b0 = blockIdx.x * 64;
    const int e0 = blockIdx.y * 64;
#pragma unroll
    for (int r = ty; r < 64; r += 4)
        tile[r][tx] = wsT[(size_t)(e0 + r) * BATCH + b0 + tx];
    __syncthreads();
#pragma unroll
    for (int r = ty; r < 64; r += 4)
        out[(size_t)(b0 + r) * E_CNT + e0 + tx] = tile[tx][r];
}

extern "C" void kernel_launch(void* const* d_in, const int* in_sizes, int n_in,
                              void* d_out, int out_size, void* d_ws, size_t ws_size,
                              hipStream_t stream) {
    const float* x  = (const float*)d_in[0];
    const float* W1 = (const float*)d_in[1];
    const float* b1 = (const float*)d_in[2];
    const float* W2 = (const float*)d_in[3];
    const float* b2 = (const float*)d_in[4];
    const float* W3 = (const float*)d_in[5];
    const float* b3 = (const float*)d_in[6];
    float* out = (float*)d_out;

    const size_t XBF_BYTES = (size_t)BATCH * 16 * sizeof(unsigned short);  // 256 KB
    const size_t WST_BYTES = (size_t)E_CNT * BATCH * sizeof(float);        // 8 MB

    const bool have_xbf = ws_size >= XBF_BYTES + WST_BYTES;
    const bool have_wst = ws_size >= WST_BYTES;

    unsigned short* xbf = (unsigned short*)d_ws;
    float* wsT = have_xbf ? (float*)((char*)d_ws + XBF_BYTES) : (float*)d_ws;

    if (have_xbf)
        prep_x_kernel<<<dim3((BATCH * 16 + 255) / 256), dim3(256), 0, stream>>>(x, xbf);

    if (have_wst) {
        mlp256_kernel<<<dim3(E_CNT * 3), dim3(256), 0, stream>>>(
            x, xbf, W1, b1, W2, b2, W3, b3, wsT, have_xbf ? 1 : 0, 1);
        transpose_out_kernel<<<dim3(BATCH / 64, E_CNT / 64), dim3(256), 0, stream>>>(
            wsT, out);
    } else {
        mlp256_kernel<<<dim3(E_CNT * 3), dim3(256), 0, stream>>>(
            x, xbf, W1, b1, W2, b2, W3, b3, out, 0, 0);
    }
}

// Round 11
// 166.758 us; speedup vs baseline: 2.5918x; 1.0330x over previous
//
#include <hip/hip_runtime.h>
#include <hip/hip_bf16.h>

// Problem geometry
#define E_CNT  256
#define D_IN   15
#define HDIM   128
#define BATCH  8192
#define NPAIR  256                  // 256 pairs of 16-row chunks per expert
#define BPE    4                    // blocks per expert -> grid 1024 = 4 blocks/CU
#define NL2E   -1.44269504088896341f

typedef float f32x4 __attribute__((ext_vector_type(4)));
typedef short bf16x8 __attribute__((ext_vector_type(8)));
typedef unsigned int uint4v __attribute__((ext_vector_type(4)));

#define MFMA16(a, b, c) __builtin_amdgcn_mfma_f32_16x16x32_bf16((a), (b), (c), 0, 0, 0)
#define SCHED_FENCE() __builtin_amdgcn_sched_barrier(0)

// bf16 via round-half-up on the bit pattern (values finite here).
static __device__ inline unsigned short f2bf_rnd(float f) {
    unsigned u = __builtin_bit_cast(unsigned, f);
    return (unsigned short)((u + 0x8000u) >> 16);
}

// sigmoid with pre-scaled input az = -z*log2(e): s = rcp(1 + 2^az).
static __device__ inline float sg(float az) {
    float e = __builtin_amdgcn_exp2f(az);
    return __builtin_amdgcn_rcpf(1.0f + e);
}

// pack two floats to a bf16 pair (lo in low half), round-half-up: 3 VALU.
static __device__ inline unsigned pack2(float lo, float hi_) {
    unsigned a = __builtin_bit_cast(unsigned, lo) + 0x8000u;
    unsigned b = __builtin_bit_cast(unsigned, hi_) + 0x8000u;
#if __has_builtin(__builtin_amdgcn_perm)
    return __builtin_amdgcn_perm(b, a, 0x07060302u);   // D = {a.b2,a.b3,b.b2,b.b3}
#else
    return (a >> 16) | (b & 0xffff0000u);
#endif
}

// v_permlane32_swap_b32: a' = {a.g0,a.g1,b.g0,b.g1}, b' = {a.g2,a.g3,b.g2,b.g3}
static __device__ inline void pl32swap(unsigned &a, unsigned &b) {
#if __has_builtin(__builtin_amdgcn_permlane32_swap)
    auto r = __builtin_amdgcn_permlane32_swap(a, b, false, false);
    a = (unsigned)r[0];
    b = (unsigned)r[1];
#else
    asm volatile("v_permlane32_swap_b32 %0, %1" : "+v"(a), "+v"(b));
#endif
}

// v_permlane16_swap_b32: a' = {a.g0,b.g0,a.g2,b.g2}, b' = {a.g1,b.g1,a.g3,b.g3}
static __device__ inline void pl16swap(unsigned &a, unsigned &b) {
#if __has_builtin(__builtin_amdgcn_permlane16_swap)
    auto r = __builtin_amdgcn_permlane16_swap(a, b, false, false);
    a = (unsigned)r[0];
    b = (unsigned)r[1];
#else
    asm volatile("v_permlane16_swap_b32 %0, %1" : "+v"(a), "+v"(b));
#endif
}

static __device__ inline f32x4 zero4() { f32x4 z = {0.f, 0.f, 0.f, 0.f}; return z; }

// Redistribute two 16x16 C-tiles (pair-packed sigmoids) into one K=32 B-frag.
// (validated on-device in R8-R10: absmax 0.0078)
static __device__ inline bf16x8 mk_bfrag(unsigned X0, unsigned X1, unsigned Y0, unsigned Y1) {
    pl32swap(X0, Y0);
    pl32swap(X1, Y1);
    pl16swap(X0, Y0);
    pl16swap(X1, Y1);
    uint4v u = {X0, X1, Y0, Y1};
    return __builtin_bit_cast(bf16x8, u);
}

// x[B][15] f32 -> xbf[B][16] bf16 with slot 15 = 1.0 (b1 partner)
__global__ __launch_bounds__(256)
void prep_x_kernel(const float* __restrict__ x, unsigned short* __restrict__ xbf)
{
    int i = blockIdx.x * 256 + threadIdx.x;
    if (i >= BATCH * 16) return;
    int row = i >> 4, k = i & 15;
    float v = (k < D_IN) ? x[row * D_IN + k] : 1.0f;
    xbf[i] = f2bf_rnd(v);
}

// 16x16x32 MFMA MLP, dual-chunk, fragment-ordered LDS (R10-validated), with
// LDS footprint compressed below 40KB -> 4 blocks/CU -> 4 waves/SIMD.
// Known-zero fragment lanes read a shared 16B zero line via pointer select
// (v_cndmask on the LDS address; quarter-uniform, no divergence):
//  w1f: 8 tiles, data lanes<32 only: [t][ln<32][8]; k=q*8+j (k==15 = b1)
//  w2f: 32 tiles (ot,kb), full: [t][64][8]
//  b2f: data q==0 only: [8 ot][16 l15][8], j==0 carries b2
//  w3f: data l15==0 only: [4 kb][4 q][8] (unscaled)
__global__ __launch_bounds__(256, 4)
void mlp256_kernel(const float* __restrict__ x, const unsigned short* __restrict__ xbf,
                   const float* __restrict__ W1, const float* __restrict__ b1,
                   const float* __restrict__ W2, const float* __restrict__ b2,
                   const float* __restrict__ W3, const float* __restrict__ b3,
                   float* __restrict__ dst, int use_xbf, int transposed)
{
    __shared__ __align__(16) unsigned short w2f[32 * 512];   // 32 KB
    __shared__ __align__(16) unsigned short w1f[8 * 256];    // 4 KB (lanes<32)
    __shared__ __align__(16) unsigned short b2f[8 * 128];    // 2 KB (q==0 lanes)
    __shared__ __align__(16) unsigned short w3f[128];        // 256 B (l15==0 lanes)
    __shared__ __align__(16) unsigned short zb[8];           // shared zero line

    const int tid  = threadIdx.x;
    const int wave = tid >> 6;
    const int lane = tid & 63;
    const int l15  = lane & 15;
    const int q    = lane >> 4;

    // grid = 1024: e = bid&255, rg = bid>>8 (0..3). Blocks e,e+256,e+512,e+768
    // share bid%8 -> same XCD under round-robin dispatch (W2 in one L2).
    const int bid = blockIdx.x;
    const int e   = bid & 255;
    const int rg  = bid >> 8;

    const float* w1p = W1 + e * (D_IN * HDIM);
    const float* b1p = b1 + e * HDIM;
    const float* w2p = W2 + e * (HDIM * HDIM);
    const float* b2p = b2 + e * HDIM;
    const float* w3p = W3 + e * HDIM;
    const float  b3v = b3[e];

    // ---- stage weights, fragment-ordered (prologue only) ----
    // W2: src (h,k) -> tile (h>>4)*4 + (k>>5), lane ((k>>3)&3)*16 + (h&15), j=k&7
    for (int i = tid; i < HDIM * HDIM; i += 256) {
        int h = i & 127, k = i >> 7;
        int t = ((h >> 4) << 2) + (k >> 5);
        int ln = (((k >> 3) & 3) << 4) + (h & 15);
        w2f[t * 512 + ln * 8 + (k & 7)] = f2bf_rnd(w2p[k * HDIM + h] * NL2E);
    }
    // W1 (+b1): 8 tiles x 32 lanes x 8; k = (ln>>4)*8 + j in 0..15
    for (int i = tid; i < 8 * 256; i += 256) {
        int t = i >> 8, ln = (i >> 3) & 31, j = i & 7;
        int k = (ln >> 4) * 8 + j, h = t * 16 + (ln & 15);
        float v = (k < D_IN) ? w1p[k * HDIM + h] : b1p[h];
        w1f[i] = f2bf_rnd(v * NL2E);
    }
    // b2: [ot][l15][8], j==0 carries the bias
    for (int i = tid; i < 8 * 128; i += 256) {
        int ot = i >> 7, l = (i >> 3) & 15, j = i & 7;
        b2f[i] = (j == 0) ? f2bf_rnd(b2p[ot * 16 + l] * NL2E) : (unsigned short)0;
    }
    // w3: [kb][q][8] unscaled; zero line
    if (tid < 128) w3f[tid] = f2bf_rnd(w3p[tid]);
    if (tid < 8)   zb[tid] = 0;

    bf16x8 ONEB;   // B[k==0]=1.0 (bias A-frag zero for k!=0 lanes -> don't-care)
#pragma unroll
    for (int j = 0; j < 8; ++j) ONEB[j] = 0;
    ONEB[0] = (short)0x3F80;

    __syncthreads();   // weights staged; waves independent from here

    // per-lane bases + selects (quarter-uniform; compile to v_cndmask on addr)
    const bool w1s = (lane < 32);
    const bool b2s = (q == 0);
    const bool w3s = (l15 == 0);
    const unsigned short* w1D = w1f + lane * 8;        // + t*256
    const unsigned short* w2B = w2f + lane * 8;        // + tile*512
    const unsigned short* b2D = b2f + l15 * 8;         // + ot*128
    const unsigned short* w3D = w3f + q * 8;           // + kb*32
    const int xoff = l15 * 16 + (q & 1) * 8;

    // pairs: p ≡ rg (mod 4), split across the 4 waves; pair p -> chunks 2p, 2p+1
    for (int p = rg + 4 * wave; p < NPAIR; p += 16) {
        const int cA = 2 * p, cB = 2 * p + 1;

        bf16x8 XA, XBv;
        if (use_xbf) {
            XA  = *reinterpret_cast<const bf16x8*>(xbf + (size_t)cA * 256 + xoff);
            XBv = *reinterpret_cast<const bf16x8*>(xbf + (size_t)cB * 256 + xoff);
        } else {
            const float* xa = x + (size_t)(cA * 16 + l15) * D_IN;
            const float* xb = x + (size_t)(cB * 16 + l15) * D_IN;
#pragma unroll
            for (int j = 0; j < 8; ++j) {
                int k = (q & 1) * 8 + j;
                XA[j]  = (short)f2bf_rnd((k < D_IN) ? xa[k] : 1.0f);
                XBv[j] = (short)f2bf_rnd((k < D_IN) ? xb[k] : 1.0f);
            }
        }

        // ---- layer 1, pairwise: two h-tiles -> one K=32 B-frag, both chunks ----
        bf16x8 H1A[4], H1B[4];
#pragma unroll
        for (int kb = 0; kb < 4; ++kb) {
            bf16x8 wa0 = *reinterpret_cast<const bf16x8*>(w1s ? (w1D + (2 * kb) * 256) : zb);
            f32x4 aa = MFMA16(wa0, XA,  zero4());
            f32x4 ba = MFMA16(wa0, XBv, zero4());
            bf16x8 wa1 = *reinterpret_cast<const bf16x8*>(w1s ? (w1D + (2 * kb + 1) * 256) : zb);
            f32x4 ab = MFMA16(wa1, XA,  zero4());
            f32x4 bb = MFMA16(wa1, XBv, zero4());
            unsigned pa0 = pack2(sg(aa[0]), sg(aa[1]));
            unsigned pa1 = pack2(sg(aa[2]), sg(aa[3]));
            unsigned pa2 = pack2(sg(ab[0]), sg(ab[1]));
            unsigned pa3 = pack2(sg(ab[2]), sg(ab[3]));
            H1A[kb] = mk_bfrag(pa0, pa1, pa2, pa3);
            unsigned pb0 = pack2(sg(ba[0]), sg(ba[1]));
            unsigned pb1 = pack2(sg(ba[2]), sg(ba[3]));
            unsigned pb2 = pack2(sg(bb[0]), sg(bb[1]));
            unsigned pb3 = pack2(sg(bb[2]), sg(bb[3]));
            H1B[kb] = mk_bfrag(pb0, pb1, pb2, pb3);
            SCHED_FENCE();
        }

        // ---- layer 2 + layer 3, pairwise: two out-tiles -> one L3 K-step ----
        f32x4 o3A = zero4(), o3B = zero4();
#pragma unroll
        for (int pt = 0; pt < 4; ++pt) {
            unsigned qa0, qa1, qa2, qa3, qb0, qb1, qb2, qb3;
            {
                const int ot = 2 * pt;
                bf16x8 wb = *reinterpret_cast<const bf16x8*>(b2s ? (b2D + ot * 128) : zb);
                f32x4 cA2 = MFMA16(wb, ONEB, zero4());
                f32x4 cB2 = MFMA16(wb, ONEB, zero4());
#pragma unroll
                for (int kb = 0; kb < 4; ++kb) {
                    bf16x8 wa = *reinterpret_cast<const bf16x8*>(w2B + (ot * 4 + kb) * 512);
                    cA2 = MFMA16(wa, H1A[kb], cA2);
                    cB2 = MFMA16(wa, H1B[kb], cB2);
                }
                qa0 = pack2(sg(cA2[0]), sg(cA2[1]));
                qa1 = pack2(sg(cA2[2]), sg(cA2[3]));
                qb0 = pack2(sg(cB2[0]), sg(cB2[1]));
                qb1 = pack2(sg(cB2[2]), sg(cB2[3]));
            }
            SCHED_FENCE();
            {
                const int ot = 2 * pt + 1;
                bf16x8 wb = *reinterpret_cast<const bf16x8*>(b2s ? (b2D + ot * 128) : zb);
                f32x4 cA2 = MFMA16(wb, ONEB, zero4());
                f32x4 cB2 = MFMA16(wb, ONEB, zero4());
#pragma unroll
                for (int kb = 0; kb < 4; ++kb) {
                    bf16x8 wa = *reinterpret_cast<const bf16x8*>(w2B + (ot * 4 + kb) * 512);
                    cA2 = MFMA16(wa, H1A[kb], cA2);
                    cB2 = MFMA16(wa, H1B[kb], cB2);
                }
                qa2 = pack2(sg(cA2[0]), sg(cA2[1]));
                qa3 = pack2(sg(cA2[2]), sg(cA2[3]));
                qb2 = pack2(sg(cB2[0]), sg(cB2[1]));
                qb3 = pack2(sg(cB2[2]), sg(cB2[3]));
            }
            bf16x8 w3a = *reinterpret_cast<const bf16x8*>(w3s ? (w3D + pt * 32) : zb);
            bf16x8 H2A = mk_bfrag(qa0, qa1, qa2, qa3);
            o3A = MFMA16(w3a, H2A, o3A);
            bf16x8 H2B = mk_bfrag(qb0, qb1, qb2, qb3);
            o3B = MFMA16(w3a, H2B, o3B);
            SCHED_FENCE();
        }

        if (q == 0) {   // output row 0 = quarter 0, reg 0; col = l15
            float vA = o3A[0] + b3v;
            float vB = o3B[0] + b3v;
            const int bbA = cA * 16 + l15;
            const int bbB = cB * 16 + l15;
            if (transposed) {
                dst[(size_t)e * BATCH + bbA] = vA;
                dst[(size_t)e * BATCH + bbB] = vB;
            } else {
                dst[(size_t)bbA * E_CNT + e] = vA;
                dst[(size_t)bbB * E_CNT + e] = vB;
            }
        }
    }
}

// wsT[e][b] (256 x 8192) -> out[b][e] (8192 x 256), 64x64 LDS tiles
__global__ __launch_bounds__(256)
void transpose_out_kernel(const float* __restrict__ wsT, float* __restrict__ out)
{
    __shared__ float tile[64][65];
    const int tx = threadIdx.x & 63;
    const int ty = threadIdx.x >> 6;
    const int b0 = blockIdx.x * 64;
    const int e0 = blockIdx.y * 64;
#pragma unroll
    for (int r = ty; r < 64; r += 4)
        tile[r][tx] = wsT[(size_t)(e0 + r) * BATCH + b0 + tx];
    __syncthreads();
#pragma unroll
    for (int r = ty; r < 64; r += 4)
        out[(size_t)(b0 + r) * E_CNT + e0 + tx] = tile[tx][r];
}

extern "C" void kernel_launch(void* const* d_in, const int* in_sizes, int n_in,
                              void* d_out, int out_size, void* d_ws, size_t ws_size,
                              hipStream_t stream) {
    const float* x  = (const float*)d_in[0];
    const float* W1 = (const float*)d_in[1];
    const float* b1 = (const float*)d_in[2];
    const float* W2 = (const float*)d_in[3];
    const float* b2 = (const float*)d_in[4];
    const float* W3 = (const float*)d_in[5];
    const float* b3 = (const float*)d_in[6];
    float* out = (float*)d_out;

    const size_t XBF_BYTES = (size_t)BATCH * 16 * sizeof(unsigned short);  // 256 KB
    const size_t WST_BYTES = (size_t)E_CNT * BATCH * sizeof(float);        // 8 MB

    const bool have_xbf = ws_size >= XBF_BYTES + WST_BYTES;
    const bool have_wst = ws_size >= WST_BYTES;

    unsigned short* xbf = (unsigned short*)d_ws;
    float* wsT = have_xbf ? (float*)((char*)d_ws + XBF_BYTES) : (float*)d_ws;

    if (have_xbf)
        prep_x_kernel<<<dim3((BATCH * 16 + 255) / 256), dim3(256), 0, stream>>>(x, xbf);

    if (have_wst) {
        mlp256_kernel<<<dim3(E_CNT * BPE), dim3(256), 0, stream>>>(
            x, xbf, W1, b1, W2, b2, W3, b3, wsT, have_xbf ? 1 : 0, 1);
        transpose_out_kernel<<<dim3(BATCH / 64, E_CNT / 64), dim3(256), 0, stream>>>(
            wsT, out);
    } else {
        mlp256_kernel<<<dim3(E_CNT * BPE), dim3(256), 0, stream>>>(
            x, xbf, W1, b1, W2, b2, W3, b3, out, 0, 0);
    }
}